// Round 1
// baseline (297.785 us; speedup 1.0000x reference)
//
#include <hip/hip_runtime.h>

#define B_ 4
#define C_ 16
#define L_ 512
#define H_ 1024
// rows per half = B*C*L = 32768 = 2^15

// Kernel 1: per-(b,c,l) dot of a length-H row with v-half, one wave per row.
// Writes results TRANSPOSED to se[half][b][l][c] so kernel 2 reads float4 over c.
__global__ __launch_bounds__(256) void dot_kernel(const float4* __restrict__ start,
                                                  const float4* __restrict__ endp,
                                                  const float4* __restrict__ v,
                                                  float* __restrict__ se) {
    const int lane       = threadIdx.x & 63;
    const int waveInBlk  = threadIdx.x >> 6;
    const int gwave      = blockIdx.x * (blockDim.x >> 6) + waveInBlk;
    const int nwaves     = gridDim.x * (blockDim.x >> 6);
    const int rows_half  = B_ * C_ * L_;          // 32768
    const int total_rows = 2 * rows_half;         // 65536

    // v fragments held in registers across all rows this wave processes.
    float4 vs[4], ve[4];
#pragma unroll
    for (int k = 0; k < 4; ++k) {
        vs[k] = v[k * 64 + lane];                 // v[:H]
        ve[k] = v[H_ / 4 + k * 64 + lane];        // v[H:]
    }

    for (int row = gwave; row < total_rows; row += nwaves) {
        const int half = row >> 15;
        const int r    = row & (rows_half - 1);
        const float4* in = (half ? endp : start) + (size_t)r * (H_ / 4);

        float acc = 0.f;
#pragma unroll
        for (int k = 0; k < 4; ++k) {
            float4 x  = in[k * 64 + lane];
            float4 vv = half ? ve[k] : vs[k];
            acc += x.x * vv.x + x.y * vv.y + x.z * vv.z + x.w * vv.w;
        }
        // 64-lane butterfly reduce
#pragma unroll
        for (int m = 32; m > 0; m >>= 1) acc += __shfl_xor(acc, m, 64);

        if (lane == 0) {
            const int b = r / (C_ * L_);
            const int c = (r / L_) & (C_ - 1);
            const int l = r & (L_ - 1);
            se[half * (B_ * L_ * C_) + (b * L_ + l) * C_ + c] = acc;
        }
    }
}

// Kernel 2: out[b,i,j,c] = s[b,i,c] + e[b,j,c], one float4 (4 c-values) per thread.
__global__ __launch_bounds__(256) void outer_kernel(const float4* __restrict__ se4,
                                                    float4* __restrict__ out4) {
    const int t  = blockIdx.x * blockDim.x + threadIdx.x;   // 0 .. B*L*L*4-1
    const int cq = t & 3;
    const int j  = (t >> 2) & (L_ - 1);
    const int bi = t >> 11;                                  // b*L + i
    float4 s = se4[bi * 4 + cq];
    const int b = bi >> 9;
    float4 e = se4[(B_ * L_ * 4) + (b * L_ + j) * 4 + cq];
    out4[t] = make_float4(s.x + e.x, s.y + e.y, s.z + e.z, s.w + e.w);
}

extern "C" void kernel_launch(void* const* d_in, const int* in_sizes, int n_in,
                              void* d_out, int out_size, void* d_ws, size_t ws_size,
                              hipStream_t stream) {
    const float4* start = (const float4*)d_in[0];
    const float4* endp  = (const float4*)d_in[1];
    const float4* v     = (const float4*)d_in[2];
    float*        se    = (float*)d_ws;      // needs 2*B*L*C floats = 256 KB
    float4*       out4  = (float4*)d_out;

    // K1: 2048 blocks x 4 waves = 8192 waves, 8 rows/wave (65536 rows total).
    dot_kernel<<<2048, 256, 0, stream>>>(start, endp, v, se);

    // K2: B*L*L*4 = 4,194,304 threads -> 16384 blocks of 256.
    outer_kernel<<<16384, 256, 0, stream>>>((const float4*)se, out4);
}